// Round 6
// baseline (247.717 us; speedup 1.0000x reference)
//
#include <hip/hip_runtime.h>

// Problem constants
#define INC    256
#define HIN    56
#define WIN    56
#define HOUT   19
#define WOUT   58
#define HW     3136          // HIN*WIN

typedef short frag8 __attribute__((ext_vector_type(8)));   // 8 bf16 bits (4 VGPRs)
typedef float f32x4 __attribute__((ext_vector_type(4)));   // MFMA accumulator

static __device__ __forceinline__ unsigned short f2bf(float f) {
    unsigned u = __float_as_uint(f);
    u += 0x7fffu + ((u >> 16) & 1u);      // round-to-nearest-even
    return (unsigned short)(u >> 16);
}

// f32 pair -> packed 2x bf16 (RNE), lo16 = a, hi16 = b
static __device__ __forceinline__ unsigned cvtpk(float a, float b) {
    unsigned r;
    asm("v_cvt_pk_bf16_f32 %0, %1, %2" : "=v"(r) : "v"(a), "v"(b));
    return r;
}

#define VMCNT(n) asm volatile("s_waitcnt vmcnt(" #n ")" ::: "memory")
#define LGKM0()  asm volatile("s_waitcnt lgkmcnt(0)" ::: "memory")
#define FENCE()  asm volatile("" ::: "memory")
#define SB0()    __builtin_amdgcn_sched_barrier(0)

// ---------------------------------------------------------------------------
// prep_weff: unchanged (R8 chunk-major layout).
//   Asw[ks2 12][o_tile 16][ksl 2][lane 64][j 8] bf16, ks2 = ks>>1, ksl = ks&1
// ---------------------------------------------------------------------------
__global__ __launch_bounds__(256) void prep_weff(
    const float* __restrict__ lego,    // [64][64][3]
    const float* __restrict__ coefs,   // [4][256][64]
    const float* __restrict__ comb,    // [4][256][64]
    unsigned short* __restrict__ Asw)
{
    __shared__ int   idxS[4];
    __shared__ float cofS[4];
    const int t  = threadIdx.x;
    const int kx = blockIdx.x;         // 0..2
    const int o  = blockIdx.y;         // 0..255
    const int wv = t >> 6, l = t & 63;

    float v  = comb[(wv * 256 + o) * 64 + l];
    int   bi = l;
    #pragma unroll
    for (int off = 32; off >= 1; off >>= 1) {
        float ov = __shfl_xor(v, off, 64);
        int   oi = __shfl_xor(bi, off, 64);
        if (ov > v || (ov == v && oi < bi)) { v = ov; bi = oi; }
    }
    if (l == 0) {
        idxS[wv] = bi;
        cofS[wv] = coefs[(wv * 256 + o) * 64 + bi];
    }
    __syncthreads();

    const int k  = kx * 256 + t;       // 0..767
    const int kh = k >> 8, c = k & 255;
    const int i  = c >> 6, cl = c & 63;
    float w = cofS[i] * lego[idxS[i] * 192 + cl * 3 + kh];

    const int o_tile = o >> 4, m = o & 15;
    const int ks = k >> 5, kc = (k >> 3) & 3, j = k & 7;
    const int ks2 = ks >> 1, ksl = ks & 1;
    Asw[((((size_t)ks2 * 16 + o_tile) * 2 + ksl) * 64 + kc * 16 + m) * 8 + j] = f2bf(w);
}

// ---------------------------------------------------------------------------
// R10 conv. Five structures (R4/R6/R8/R9) all pinned at 72-77us with the
// machine ~90% idle and duration insensitive to HBM level (warm-replay rows:
// half the bytes, same time). Remaining shared suspects: (a) barrier-aligned
// same-line L2 herd on Asw (all ~76 blocks of an XCD read the SAME 32KB
// A-chunk each round), (b) per-block fixed costs x 608 blocks.
// R10: TWO (b,h) tiles per block -- (by,h) and (by+16,h) -- sharing ONE set
// of A registers per chunk (A L2-traffic and barriers per unit work halved;
// grid 304), plus a per-block rotation of the cq chunk order
// (rot=(bid>>3)&3: same-XCD blocks request DIFFERENT A-chunks in the same
// wall-clock round, de-phasing the herd 4x; K-sum order change only).
// Pipeline = R9's proven discipline, re-derived:
//   iter q: compute(q) [compiler waits vmcnt(32): retires A(q), keeps
//           L(q+1)=32]; LOADA(q+1) [8]; VMCNT(8) retires L(q+1) keeps
//           A(q+1); W(q+1) both tiles; LOADL(q+2) both tiles [32];
//           LGKM0; s_barrier.   Tail: q=10 no LOADL; q=11 compute only.
// Regs: acc 128 AGPR + A 32 + Lv 32 + ~40 misc ~= 105 arch / 233 unified
// <= (256,2) cap 256 -- no spill (R7 lesson; canary = WRITE_SIZE).
// LDS 32 KB (2 bufs x 2 tiles x 8KB). 2 blocks/CU possible; grid 304.
// ---------------------------------------------------------------------------
__global__ __launch_bounds__(256, 2) void conv_mfma(
    const float* __restrict__ x,             // [32][256][56][56]
    const unsigned short* __restrict__ Asw,  // [12][16][2][64][8]
    float* __restrict__ out)                 // [32][256][19][58]
{
    __shared__ unsigned short Xs[2][2][4096];   // [buf][tile], 32 KB total

    const int t  = threadIdx.x;
    const int h  = blockIdx.x;               // 0..18
    const int by = blockIdx.y;               // 0..15
    const int bA = by, bB = by + 16;
    const int l  = t & 63;
    const int lo = l & 15;
    const int hi = l >> 4;
    const int wv = t >> 6;

    const int lin = by * 19 + h;
    const int rot = (lin >> 3) & 3;          // same-XCD blocks get 0,1,2,3

    // ---- staging constants (R9 mapping): thread = (kg 0..7, cw 0..31)
    const int cw   = t & 31;
    const int kg   = (t >> 5) & 7;
    const int kslw = kg >> 2, kcw = kg & 3;
    const int c1u  = cw + 32;                        // unclamped col 32..63
    const int c1   = (c1u < WIN) ? c1u : (WIN - 1);  // value-clamped
    const int cdelta = c1 - cw;
    int voff[8];
    #pragma unroll
    for (int j = 0; j < 8; ++j) voff[j] = (kg * 8 + j) * HW + cw;
    // write slots: fragment (kslw, kcw, col); slot uses UNCLAMPED col
    const int ws0 = ((kslw * 4 + (cw  >> 4)) * 64 + kcw * 16 + (cw  & 15)) * 8;
    const int ws1 = ((kslw * 4 + (c1u >> 4)) * 64 + kcw * 16 + (c1u & 15)) * 8;

    const float* xbA = x + (size_t)bA * (INC * HW);
    const float* xbB = x + (size_t)bB * (INC * HW);
    const frag8* Afw = (const frag8*)Asw + l;   // + qe*2048 + wv*512 + ot*128 + ksl*64

    f32x4 accA[4][4], accB[4][4];
    #pragma unroll
    for (int ot = 0; ot < 4; ++ot)
        #pragma unroll
        for (int wt = 0; wt < 4; ++wt) {
            accA[ot][wt] = (f32x4){0.f, 0.f, 0.f, 0.f};
            accB[ot][wt] = (f32x4){0.f, 0.f, 0.f, 0.f};
        }

    frag8 A[4][2];
    float LvA[16], LvB[16];

    // rotated chunk id: kh bits kept, cq rotated per block
#define QE(qv) (((qv) & 12) | (((qv) + rot) & 3))

    // 16 coalesced dword loads for one tile (always issued; zmask kills pad)
#define LOADL_T(LV, XB, QEV) do {                                          \
        const int qe_ = (QEV);                                             \
        const int row_ = 3 * h - 1 + (qe_ >> 2);                           \
        const int rc_  = row_ < 0 ? 0 : row_;                              \
        const float zm_ = row_ < 0 ? 0.f : 1.f;                            \
        const float* xq_ = (XB) + (size_t)(qe_ & 3) * 64 * HW              \
                                + (size_t)rc_ * WIN;                       \
        _Pragma("unroll")                                                  \
        for (int j_ = 0; j_ < 8; ++j_) {                                   \
            LV[j_]     = xq_[voff[j_]] * zm_;                              \
            LV[8 + j_] = xq_[voff[j_] + cdelta] * zm_;                     \
        }                                                                  \
    } while (0)

#define LOADA_T(QEV) do {                                                  \
        const int qe_ = (QEV);                                             \
        _Pragma("unroll")                                                  \
        for (int ot_ = 0; ot_ < 4; ++ot_)                                  \
            _Pragma("unroll")                                              \
            for (int ksl_ = 0; ksl_ < 2; ++ksl_)                           \
                A[ot_][ksl_] = Afw[qe_ * 2048 + wv * 512 + ot_ * 128 + ksl_ * 64]; \
    } while (0)

#define W_T(BP, TL, LV) do {                                               \
        union { frag8 fr; unsigned u[4]; } P_;                             \
        P_.u[0] = cvtpk(LV[0], LV[1]);                                     \
        P_.u[1] = cvtpk(LV[2], LV[3]);                                     \
        P_.u[2] = cvtpk(LV[4], LV[5]);                                     \
        P_.u[3] = cvtpk(LV[6], LV[7]);                                     \
        *(frag8*)&Xs[BP][TL][ws0] = P_.fr;                                 \
        P_.u[0] = cvtpk(LV[8],  LV[9]);                                    \
        P_.u[1] = cvtpk(LV[10], LV[11]);                                   \
        P_.u[2] = cvtpk(LV[12], LV[13]);                                   \
        P_.u[3] = cvtpk(LV[14], LV[15]);                                   \
        *(frag8*)&Xs[BP][TL][ws1] = P_.fr;                                 \
    } while (0)

#define COMPUTE_T(BP, TL, ACC) do {                                        \
        const frag8* Xf_ = (const frag8*)&Xs[BP][TL][0] + l;               \
        _Pragma("unroll")                                                  \
        for (int ksl_ = 0; ksl_ < 2; ++ksl_)                               \
            _Pragma("unroll")                                              \
            for (int wt_ = 0; wt_ < 4; ++wt_) {                            \
                frag8 B_ = Xf_[(ksl_ * 4 + wt_) * 64];                     \
                _Pragma("unroll")                                          \
                for (int ot_ = 0; ot_ < 4; ++ot_)                          \
                    ACC[ot_][wt_] = __builtin_amdgcn_mfma_f32_16x16x32_bf16( \
                        A[ot_][ksl_], B_, ACC[ot_][wt_], 0, 0, 0);         \
            }                                                              \
    } while (0)

    // ---- prologue
    LOADA_T(QE(0));
    SB0();
    LOADL_T(LvA, xbA, QE(0));
    LOADL_T(LvB, xbB, QE(0));
    SB0();
    VMCNT(0);
    W_T(0, 0, LvA);
    W_T(0, 1, LvB);
    LOADL_T(LvA, xbA, QE(1));
    LOADL_T(LvB, xbB, QE(1));
    SB0();
    LGKM0();
    __builtin_amdgcn_s_barrier();
    FENCE();

    #pragma unroll
    for (int q = 0; q < 12; ++q) {
        const int bp = q & 1;
        // compiler waits vmcnt(32) for A(q) here, keeping L(q+1)=32 in flight
        COMPUTE_T(bp, 0, accA);
        COMPUTE_T(bp, 1, accB);

        if (q < 11) {
            SB0();                        // compute(q) done before A-reg reuse
            LOADA_T(QE(q + 1));           // FIFO: newer than L(q+1)
            SB0();
            VMCNT(8);                     // retire L(q+1)(32); keep A(q+1)(8)
            W_T((q + 1) & 1, 0, LvA);
            W_T((q + 1) & 1, 1, LvB);
            if (q < 10) {
                LOADL_T(LvA, xbA, QE(q + 2));   // reuse L regs (WAR via cvt)
                LOADL_T(LvB, xbB, QE(q + 2));
            }
            SB0();
            LGKM0();                      // ds_writes visible before barrier
            __builtin_amdgcn_s_barrier();
            FENCE();
        }
    }

    // ---- store: out col = n+1 for n=0..55; cols 0 and 57 are exact zeros
#define STORE_T(BV, ACC) do {                                              \
        _Pragma("unroll")                                                  \
        for (int ot_ = 0; ot_ < 4; ++ot_)                                  \
            _Pragma("unroll")                                              \
            for (int r_ = 0; r_ < 4; ++r_) {                               \
                int o_ = wv * 64 + ot_ * 16 + hi * 4 + r_;                 \
                float* orow_ = out + ((size_t)((BV) * 256 + o_) * HOUT + h) * WOUT; \
                _Pragma("unroll")                                          \
                for (int wt_ = 0; wt_ < 4; ++wt_) {                        \
                    int n_ = wt_ * 16 + lo;                                \
                    if (n_ < 56) orow_[n_ + 1] = ACC[ot_][wt_][r_];        \
                }                                                          \
                if (lo == 0) orow_[0]  = 0.f;                              \
                if (lo == 1) orow_[57] = 0.f;                              \
            }                                                              \
    } while (0)

    STORE_T(bA, accA);
    STORE_T(bB, accB);
}

extern "C" void kernel_launch(void* const* d_in, const int* in_sizes, int n_in,
                              void* d_out, int out_size, void* d_ws, size_t ws_size,
                              hipStream_t stream) {
    const float* x     = (const float*)d_in[0];   // (32,256,56,56)
    const float* lego  = (const float*)d_in[1];   // (64,64,3,1)
    const float* coefs = (const float*)d_in[2];   // (4,256,64,1,1)
    const float* comb  = (const float*)d_in[3];   // (4,256,64,1,1)
    float* out = (float*)d_out;                   // (32,256,19,58)

    unsigned short* Asw = (unsigned short*)d_ws;  // 196,608 bf16 = 384 KB

    prep_weff<<<dim3(3, 256), 256, 0, stream>>>(lego, coefs, comb, Asw);
    conv_mfma<<<dim3(HOUT, 16), 256, 0, stream>>>(x, Asw, out);
}

// Round 7
// 194.962 us; speedup vs baseline: 1.2706x; 1.2706x over previous
//
#include <hip/hip_runtime.h>

// Problem constants
#define INC    256
#define HIN    56
#define WIN    56
#define HOUT   19
#define WOUT   58
#define HW     3136          // HIN*WIN

typedef short frag8 __attribute__((ext_vector_type(8)));   // 8 bf16 bits (4 VGPRs)
typedef float f32x4 __attribute__((ext_vector_type(4)));   // MFMA accumulator

static __device__ __forceinline__ unsigned short f2bf(float f) {
    unsigned u = __float_as_uint(f);
    u += 0x7fffu + ((u >> 16) & 1u);      // round-to-nearest-even
    return (unsigned short)(u >> 16);
}

// f32 pair -> packed 2x bf16 (RNE), lo16 = a, hi16 = b
static __device__ __forceinline__ unsigned cvtpk(float a, float b) {
    unsigned r;
    asm("v_cvt_pk_bf16_f32 %0, %1, %2" : "=v"(r) : "v"(a), "v"(b));
    return r;
}

#define VMCNT(n) asm volatile("s_waitcnt vmcnt(" #n ")" ::: "memory")
#define LGKM0()  asm volatile("s_waitcnt lgkmcnt(0)" ::: "memory")
#define FENCE()  asm volatile("" ::: "memory")
#define SB0()    __builtin_amdgcn_sched_barrier(0)

// ---------------------------------------------------------------------------
// prep_weff: unchanged (R8 chunk-major layout).
//   Asw[ks2 12][o_tile 16][ksl 2][lane 64][j 8] bf16, ks2 = ks>>1, ksl = ks&1
// ---------------------------------------------------------------------------
__global__ __launch_bounds__(256) void prep_weff(
    const float* __restrict__ lego,    // [64][64][3]
    const float* __restrict__ coefs,   // [4][256][64]
    const float* __restrict__ comb,    // [4][256][64]
    unsigned short* __restrict__ Asw)
{
    __shared__ int   idxS[4];
    __shared__ float cofS[4];
    const int t  = threadIdx.x;
    const int kx = blockIdx.x;         // 0..2
    const int o  = blockIdx.y;         // 0..255
    const int wv = t >> 6, l = t & 63;

    float v  = comb[(wv * 256 + o) * 64 + l];
    int   bi = l;
    #pragma unroll
    for (int off = 32; off >= 1; off >>= 1) {
        float ov = __shfl_xor(v, off, 64);
        int   oi = __shfl_xor(bi, off, 64);
        if (ov > v || (ov == v && oi < bi)) { v = ov; bi = oi; }
    }
    if (l == 0) {
        idxS[wv] = bi;
        cofS[wv] = coefs[(wv * 256 + o) * 64 + bi];
    }
    __syncthreads();

    const int k  = kx * 256 + t;       // 0..767
    const int kh = k >> 8, c = k & 255;
    const int i  = c >> 6, cl = c & 63;
    float w = cofS[i] * lego[idxS[i] * 192 + cl * 3 + kh];

    const int o_tile = o >> 4, m = o & 15;
    const int ks = k >> 5, kc = (k >> 3) & 3, j = k & 7;
    const int ks2 = ks >> 1, ksl = ks & 1;
    Asw[((((size_t)ks2 * 16 + o_tile) * 2 + ksl) * 64 + kc * 16 + m) * 8 + j] = f2bf(w);
}

// ---------------------------------------------------------------------------
// R11 conv. Cycle accounting across R4..R10 (MfmaUtil vs required MFMA cycles
// implies ~1GHz effective clock) shows ~6k cycles/round vs ~1.5k issue work:
// every variant so far gave loads <=1 round of latency cover, and all waves
// stall together on the same wait. R11 buys TRUE depth-2-round cover with
// registers (occupancy proven non-binding: R4@20 waves/CU == R9@12):
//   __launch_bounds__(256,2)  -> 256-reg unified cap, no spill by construction
//   3 L-register sets (48 VGPR) + 4 LDS buffers (32KB)
//   W(q+1) at TOP of round q consumes L(q+1) issued at BOTTOM of round q-2
//     -> 2 full rounds + 2 barriers of cover for every x-load
// vmcnt ledger (steady round q, entering outstanding = L(q+1)16 A(q)8
// L(q+2)16 = 40): VMCNT(24) retires exactly L(q+1); compiler's A(q) wait =
// vmcnt(16) keeps L(q+2); round bottom issues A(q+1) then L(q+3) -> 40 again.
// Tails: r0 VMCNT(16) [prologue retired A0+L0], r10 VMCNT(8), r11 none.
// Sets: L(k) -> set[k%3]; W(q+1) reads set[(q+1)%3]; LOADL(q+3) -> set[q%3]
// (freed by W(q) last round). Buffers mod 4: W(q+1)->buf[(q+1)&3], compute(q)
// ->buf[q&3]; reuse distance 4 >= 2 barriers -> single barrier/round safe.
// Everything else = R9 (fragment-linear bf16 LDS, conflict-free b128 reads,
// zmask padding, store epilogue, grid 608).
// ---------------------------------------------------------------------------
__global__ __launch_bounds__(256, 2) void conv_mfma(
    const float* __restrict__ x,             // [32][256][56][56]
    const unsigned short* __restrict__ Asw,  // [12][16][2][64][8]
    float* __restrict__ out)                 // [32][256][19][58]
{
    __shared__ unsigned short Xs[4][4096];   // 4 x 8 KB bf16, fragment-linear

    const int t  = threadIdx.x;
    const int h  = blockIdx.x;               // 0..18
    const int b  = blockIdx.y;               // 0..31
    const int l  = t & 63;
    const int lo = l & 15;
    const int hi = l >> 4;
    const int wv = t >> 6;

    // ---- staging constants (R9 mapping): thread = (kg 0..7, cw 0..31)
    const int cw   = t & 31;
    const int kg   = (t >> 5) & 7;
    const int kslw = kg >> 2, kcw = kg & 3;
    const int c1u  = cw + 32;                        // unclamped col 32..63
    const int c1   = (c1u < WIN) ? c1u : (WIN - 1);  // value-clamped
    int voff[16];
    #pragma unroll
    for (int j = 0; j < 8; ++j) {
        voff[j]     = (kg * 8 + j) * HW + cw;
        voff[8 + j] = (kg * 8 + j) * HW + c1;
    }
    // write slots: fragment (kslw, kcw, col); slot uses UNCLAMPED col
    const int ws0 = ((kslw * 4 + (cw  >> 4)) * 64 + kcw * 16 + (cw  & 15)) * 8;
    const int ws1 = ((kslw * 4 + (c1u >> 4)) * 64 + kcw * 16 + (c1u & 15)) * 8;

    const float* xb = x + (size_t)b * (INC * HW);
    const frag8* Afw = (const frag8*)Asw + l;    // + q*2048 + wv*512 + ot*128 + ksl*64

    f32x4 acc[4][4];
    #pragma unroll
    for (int ot = 0; ot < 4; ++ot)
        #pragma unroll
        for (int wt = 0; wt < 4; ++wt)
            acc[ot][wt] = (f32x4){0.f, 0.f, 0.f, 0.f};

    frag8 A[4][2];
    float LvA[16], LvB[16], LvC[16];

    auto LOADL = [&](float (&Lv)[16], int q) {
        const int kh  = q >> 2, cq = q & 3;
        const int row = 3 * h - 1 + kh;
        const int rc  = row < 0 ? 0 : row;
        const float zmask = row < 0 ? 0.f : 1.f;
        const float* xq = xb + (size_t)cq * 64 * HW + (size_t)rc * WIN;
        #pragma unroll
        for (int i = 0; i < 16; ++i) Lv[i] = xq[voff[i]] * zmask;
    };

    auto LOADA = [&](int q) {
        #pragma unroll
        for (int ot = 0; ot < 4; ++ot)
            #pragma unroll
            for (int ksl = 0; ksl < 2; ++ksl)
                A[ot][ksl] = Afw[q * 2048 + wv * 512 + ot * 128 + ksl * 64];
    };

    auto W = [&](float (&Lv)[16], int buf) {
        union { frag8 fr; unsigned u[4]; } P;
        P.u[0] = cvtpk(Lv[0], Lv[1]);
        P.u[1] = cvtpk(Lv[2], Lv[3]);
        P.u[2] = cvtpk(Lv[4], Lv[5]);
        P.u[3] = cvtpk(Lv[6], Lv[7]);
        *(frag8*)&Xs[buf][ws0] = P.fr;
        P.u[0] = cvtpk(Lv[8],  Lv[9]);
        P.u[1] = cvtpk(Lv[10], Lv[11]);
        P.u[2] = cvtpk(Lv[12], Lv[13]);
        P.u[3] = cvtpk(Lv[14], Lv[15]);
        *(frag8*)&Xs[buf][ws1] = P.fr;
    };

    auto COMPUTE = [&](int buf) {
        const frag8* Xf = (const frag8*)&Xs[buf][0] + l;
        #pragma unroll
        for (int ksl = 0; ksl < 2; ++ksl) {
            #pragma unroll
            for (int wt = 0; wt < 4; ++wt) {
                frag8 B = Xf[(ksl * 4 + wt) * 64];
                #pragma unroll
                for (int ot = 0; ot < 4; ++ot)
                    acc[ot][wt] = __builtin_amdgcn_mfma_f32_16x16x32_bf16(
                        A[ot][ksl], B, acc[ot][wt], 0, 0, 0);
            }
        }
    };

    // ---- prologue: A0, L0->LvA, L1->LvB, L2->LvC; retire A0+L0; W(0)
    LOADA(0);
    SB0();
    LOADL(LvA, 0);
    LOADL(LvB, 1);
    LOADL(LvC, 2);
    SB0();
    VMCNT(32);                           // retire A0+L0; keep L1,L2
    W(LvA, 0);
    SB0();
    LGKM0();
    __builtin_amdgcn_s_barrier();
    FENCE();

    // ROUND(q): [VM] W(q+1); compute(q); LOADA(q+1); LOADL(q+3); barrier
#define ROUND(q, SW, SL, VM)                                               \
    do {                                                                   \
        VM;                                                                \
        W(SW, (q + 1) & 3);                                                \
        COMPUTE(q & 3);                                                    \
        SB0();                  /* compute(q) done before A-reg reuse  */  \
        LOADA(q + 1);           /* FIFO: A(q+1) older than L(q+3)      */  \
        SB0();                                                             \
        LOADL(SL, q + 3);                                                  \
        SB0();                                                             \
        LGKM0();                /* ds_writes visible before barrier    */  \
        __builtin_amdgcn_s_barrier();                                      \
        FENCE();                                                           \
    } while (0)

    ROUND(0, LvB, LvA, VMCNT(16));       // enter: L1,L2=32; retire L1
    ROUND(1, LvC, LvB, VMCNT(24));       // steady: L(q+1),A(q),L(q+2)=40
    ROUND(2, LvA, LvC, VMCNT(24));
    ROUND(3, LvB, LvA, VMCNT(24));
    ROUND(4, LvC, LvB, VMCNT(24));
    ROUND(5, LvA, LvC, VMCNT(24));
    ROUND(6, LvB, LvA, VMCNT(24));
    ROUND(7, LvC, LvB, VMCNT(24));
    ROUND(8, LvA, LvC, VMCNT(24));

    // round 9: no LOADL (L12 doesn't exist)
    VMCNT(24);                           // enter: L10,A9,L11=40; retire L10
    W(LvB, 10 & 3);
    COMPUTE(9 & 3);
    SB0();
    LOADA(10);
    SB0();
    LGKM0();
    __builtin_amdgcn_s_barrier();
    FENCE();

    // round 10: no LOADL
    VMCNT(8);                            // enter: L11,A10=24; retire L11
    W(LvC, 11 & 3);
    COMPUTE(10 & 3);
    SB0();
    LOADA(11);
    SB0();
    LGKM0();
    __builtin_amdgcn_s_barrier();
    FENCE();

    // round 11: compute only (compiler waits A11)
    COMPUTE(11 & 3);

    // ---- store: out col = n+1 for n=0..55; cols 0 and 57 are exact zeros
    #pragma unroll
    for (int ot = 0; ot < 4; ++ot) {
        #pragma unroll
        for (int r = 0; r < 4; ++r) {
            int o = wv * 64 + ot * 16 + hi * 4 + r;
            float* orow = out + ((size_t)(b * 256 + o) * HOUT + h) * WOUT;
            #pragma unroll
            for (int wt = 0; wt < 4; ++wt) {
                int n = wt * 16 + lo;
                if (n < 56) orow[n + 1] = acc[ot][wt][r];
            }
            if (lo == 0) orow[0]  = 0.f;
            if (lo == 1) orow[57] = 0.f;
        }
    }
}

extern "C" void kernel_launch(void* const* d_in, const int* in_sizes, int n_in,
                              void* d_out, int out_size, void* d_ws, size_t ws_size,
                              hipStream_t stream) {
    const float* x     = (const float*)d_in[0];   // (32,256,56,56)
    const float* lego  = (const float*)d_in[1];   // (64,64,3,1)
    const float* coefs = (const float*)d_in[2];   // (4,256,64,1,1)
    const float* comb  = (const float*)d_in[3];   // (4,256,64,1,1)
    float* out = (float*)d_out;                   // (32,256,19,58)

    unsigned short* Asw = (unsigned short*)d_ws;  // 196,608 bf16 = 384 KB

    prep_weff<<<dim3(3, 256), 256, 0, stream>>>(lego, coefs, comb, Asw);
    conv_mfma<<<dim3(HOUT, 32), 256, 0, stream>>>(x, Asw, out);
}